// Round 2
// baseline (274.631 us; speedup 1.0000x reference)
//
#include <hip/hip_runtime.h>

// Round 11: BK=64 GEMM core, correct 8-slot XOR swizzle.
// - Theory from round-10 counters: latency-bound (all pipes <15%); the
//   __syncthreads() vmcnt drain exposes full DMA latency every K-step because
//   the compute phase (8 MFMA ~ 64 cy) << latency. BK=64 doubles the phase to
//   16x v_mfma_f32_32x32x16_f16 (~545 SIMD-cy) which covers L2 latency.
// - Round-10 swizzle was wrong for 64B rows (bank conflicts DOUBLED to 6.3M):
//   with 128B rows (BK=64 f16) the b128 slot index is 3 bits; slot ^= row&7
//   spreads 8 lanes/slot = the ds_read_b128 floor. Baked into f16 global
//   layouts (cvt_w for W, attn y-store) so global_load_lds dest stays linear.
// - LDS [2][128][64] f16 x2 = 64 KB -> 2 blocks/CU. Frag reads are pure
//   contiguous b128. fp32-A staging (gemm_qkv) split into two half-tiles
//   interleaved inside the MFMA phase (hidden; pa regs = 16 VGPR).
// Attention kernel unchanged from round 10 (passed) except the shared swz().

using f16    = _Float16;
using f16x4  = __attribute__((ext_vector_type(4))) _Float16;
using f16x8  = __attribute__((ext_vector_type(8))) _Float16;
using f32x4  = __attribute__((ext_vector_type(4))) float;
using f32x16 = __attribute__((ext_vector_type(16))) float;

static constexpr int S = 1024, Dm = 1024, NH = 16, HD = 64;

#if __has_builtin(__builtin_amdgcn_mfma_f32_32x32x16_f16)
#define USE_G32 1
#define MFMA32(ACC, A_, B_) \
    (ACC) = __builtin_amdgcn_mfma_f32_32x32x16_f16((A_), (B_), (ACC), 0, 0, 0)
#else
#define USE_G32 0
#endif

#if __has_builtin(__builtin_amdgcn_mfma_f32_16x16x32_f16) && \
    __has_builtin(__builtin_amdgcn_mfma_f32_16x16x16f16)
#define USE_A16 1
#define MFMA16K32(ACC, A_, B_) \
    (ACC) = __builtin_amdgcn_mfma_f32_16x16x32_f16((A_), (B_), (ACC), 0, 0, 0)
#define MFMA16(ACC, A_, B_) \
    (ACC) = __builtin_amdgcn_mfma_f32_16x16x16f16((A_), (B_), (ACC), 0, 0, 0)
#else
#define USE_A16 0
#endif

#define LO4(v) __builtin_shufflevector((v), (v), 0, 1, 2, 3)
#define HI4(v) __builtin_shufflevector((v), (v), 4, 5, 6, 7)

__device__ __forceinline__ f16x4 cvt4(float4 a) {
    f16x4 r; r[0] = (f16)a.x; r[1] = (f16)a.y; r[2] = (f16)a.z; r[3] = (f16)a.w;
    return r;
}

// hd permutation for qh/kh (K=32 QK MFMA), unchanged from round 10 (verified).
__device__ __forceinline__ int pcol64(int k) {
#if USE_A16
    return ((k >> 3) & 3) * 16 + ((k >> 5) << 3) + (k & 7);
#else
    return ((k >> 2) & 3) * 16 + ((k >> 4) << 2) + (k & 3);
#endif
}

// Bank swizzle for 64-f16 (128 B) row tiles: XOR the 3-bit 16B-slot index with
// row&7. Involution; same function used by writer (cvt_w / attn y-store /
// stageA) and reader (frag loads). 8 slots x 8 lanes = ds_read_b128 floor.
__device__ __forceinline__ int swz(int row, int col) {
    return (col & ~63) | ((((col >> 3) ^ row) & 7) << 3) | (col & 7);
}

// mode 0: [B,H,S,HD] f16 hd-permuted; 1: [B,H,HD,S] f16; 2: fp32 row-major
__device__ __forceinline__ void store_out(void* out, int mode, int m, int n, float v) {
    if (mode == 2) {
        ((float*)out)[(size_t)m * Dm + n] = v;
    } else {
        const int b_ = m >> 10, s_ = m & 1023, h_ = n >> 6, hd_ = n & 63;
        const size_t idx = (mode == 0)
            ? (((size_t)(b_ * NH + h_) * S + s_) * HD + pcol64(hd_))
            : (((size_t)(b_ * NH + h_) * HD + hd_) * S + s_);
        ((f16*)out)[idx] = (f16)v;
    }
}

#if __has_builtin(__builtin_amdgcn_global_load_lds)
#define HAS_GLL 1
#else
#define HAS_GLL 0
#endif

__device__ __forceinline__ void gll16(const f16* g, f16* l) {
#if HAS_GLL
    __builtin_amdgcn_global_load_lds(
        (const __attribute__((address_space(1))) void*)g,
        (__attribute__((address_space(3))) void*)l, 16, 0, 0);
#else
    *(uint4*)l = *(const uint4*)g;   // sync fallback; drained by barrier
#endif
}

// ---------------------------------------------------------------------------
// fp32 W -> f16, swizzled layout. grid (1024, nmat); one float4 per thread.
// k&7 in {0,4}: a float4 stays inside one 8-f16 slot, so swz maps it cleanly.
// ---------------------------------------------------------------------------
__global__ __launch_bounds__(256)
void cvt_w(const float* __restrict__ s0, const float* __restrict__ s1,
           const float* __restrict__ s2, f16* __restrict__ dst)
{
    const int z = blockIdx.y;
    const float* src = (z == 0) ? s0 : (z == 1) ? s1 : s2;
    const int e = blockIdx.x * 256 + threadIdx.x;   // float4 id within matrix
    const int n = e >> 8;
    const int k = (e & 255) * 4;
    const float4 v = *(const float4*)(src + (size_t)n * Dm + k);
    *(f16x4*)(dst + (size_t)z * Dm * Dm + (size_t)n * Dm + swz(n, k)) = cvt4(v);
}

// ---------------------------------------------------------------------------
// out = relu(A @ W^T + bias). W: f16 swizzled (cvt_w). 128x128 tile, BK=64,
// dbuf, 4 waves (2x2), 64x64/wave via 2x2 32x32 frags, 16 MFMA per K-step.
// ADMA=0: A fp32, reg-staged in two half-tiles interleaved with the MFMAs.
// ADMA=1: A f16 swizzled (y from attn), DMA-staged like W.
// One barrier per K-step (same proven sync structure as rounds 9/10):
//   barrier -> DMA next tile into buf cur^1 (+ reg-stage A halves, hidden
//   between MFMA slices) -> 16 MFMAs on buf cur.
// 32x32x16 frags: A lane l: A[m=l&31][k=8*(l>>5)+j]; C/D reg i:
// row = 8*(i>>2) + 4*(l>>5) + (i&3), col = l&31 (HW-verified, round 10).
// ---------------------------------------------------------------------------
template <int ADMA>
__device__ __forceinline__ void gemm_core(const void* __restrict__ A,
                                          const f16* __restrict__ Wf,
                                          const float* __restrict__ bias,
                                          void* __restrict__ out, int mode)
{
    const int tid = threadIdx.x;
    const int bm = blockIdx.x, bn = blockIdx.y;
#if USE_G32
    __shared__ alignas(16) f16 As[2][128][64];   // 32 KB
    __shared__ alignas(16) f16 Ws[2][128][64];   // 32 KB  (total 64 KB -> 2 blk/CU)

    const int lane = tid & 63, wave = tid >> 6;
    const int l31 = lane & 31, kh = lane >> 5;
    const int wm = wave & 1, wn = wave >> 1;

    // DMA mapping: round i, wave w -> 1KB chunk (i*4+w) = rows [(i*4+w)*8, +8);
    // lane dest byte = chunk_base + lane*16 (exactly the HW wave-linear rule).
    const int drow = lane >> 3;            // 0..7
    const int dcol = (lane & 7) * 8;       // f16 col {0..56}
    const f16* Wsrc = Wf + (size_t)(bn * 128) * Dm + dcol;
    const f16* Asrc = (const f16*)A + (size_t)(bm * 128) * Dm + dcol;

    auto dma = [&](int k0, int cur) {
#pragma unroll
        for (int i = 0; i < 4; ++i) {
            const int r = (i * 4 + wave) * 8 + drow;
            gll16(Wsrc + (size_t)r * Dm + k0, &Ws[cur][r][dcol]);
        }
        if (ADMA) {
#pragma unroll
            for (int i = 0; i < 4; ++i) {
                const int r = (i * 4 + wave) * 8 + drow;
                gll16(Asrc + (size_t)r * Dm + k0, &As[cur][r][dcol]);
            }
        }
    };

    // fp32 A reg staging (ADMA=0): 2 threads/row, 16 fp32 per thread per half.
    const int ar = tid >> 1;               // row 0..127
    const int ah = tid & 1;                // col half within a 32-col group
    const float* Af = (const float*)A + (size_t)(bm * 128 + ar) * Dm + ah * 16;

    float4 pa[4];
    auto prefA = [&](int k0, int h) {
#pragma unroll
        for (int j = 0; j < 4; ++j)
            pa[j] = *(const float4*)(Af + k0 + h * 32 + j * 4);
    };
    auto stageA = [&](int cur, int h) {
#pragma unroll
        for (int j2 = 0; j2 < 2; ++j2) {
            f16x8 v;
            const float4 a0 = pa[j2 * 2], a1 = pa[j2 * 2 + 1];
            v[0] = (f16)a0.x; v[1] = (f16)a0.y; v[2] = (f16)a0.z; v[3] = (f16)a0.w;
            v[4] = (f16)a1.x; v[5] = (f16)a1.y; v[6] = (f16)a1.z; v[7] = (f16)a1.w;
            const int slot = (h * 4 + ah * 2 + j2) ^ (ar & 7);
            *(f16x8*)&As[cur][ar][slot * 8] = v;
        }
    };

    f32x16 acc[2][2] = {};

    auto kslice = [&](int cur, int s) {
        const int slot = ((s * 2 + kh) ^ (l31 & 7)) * 8;
        const f16x8 af0 = *(const f16x8*)&As[cur][wm * 64 + l31][slot];
        const f16x8 af1 = *(const f16x8*)&As[cur][wm * 64 + 32 + l31][slot];
        const f16x8 bf0 = *(const f16x8*)&Ws[cur][wn * 64 + l31][slot];
        const f16x8 bf1 = *(const f16x8*)&Ws[cur][wn * 64 + 32 + l31][slot];
        MFMA32(acc[0][0], af0, bf0);
        MFMA32(acc[0][1], af0, bf1);
        MFMA32(acc[1][0], af1, bf0);
        MFMA32(acc[1][1], af1, bf1);
    };

    constexpr int NIT = Dm / 64;           // 16
    dma(0, 0);
    if (!ADMA) { prefA(0, 0); stageA(0, 0); prefA(0, 1); stageA(0, 1); }
    for (int it = 0; it < NIT; ++it) {
        const int cur = it & 1;
        __syncthreads();                   // drains DMA for buf cur; one/iter
        const bool more = (it < NIT - 1);
        if (more) dma((it + 1) * 64, cur ^ 1);
        if (!ADMA && more) prefA((it + 1) * 64, 0);
        kslice(cur, 0);
        kslice(cur, 1);
        if (!ADMA && more) { stageA(cur ^ 1, 0); prefA((it + 1) * 64, 1); }
        kslice(cur, 2);
        if (!ADMA && more) stageA(cur ^ 1, 1);
        kslice(cur, 3);
    }

    // epilogue (C/D map verified in round 10)
#pragma unroll
    for (int g2 = 0; g2 < 2; ++g2) {
        const int col = bn * 128 + wn * 64 + g2 * 32 + l31;
        const float bb = bias[col];
#pragma unroll
        for (int g = 0; g < 2; ++g)
#pragma unroll
            for (int blk = 0; blk < 4; ++blk) {
                const int row0 = bm * 128 + wm * 64 + g * 32 + 8 * blk + 4 * kh;
                if (mode == 1) {   // [B,H,HD,S]: 4 consecutive s -> packed b64
                    const int b_ = row0 >> 10, s_ = row0 & 1023;
                    const int h_ = col >> 6, hd_ = col & 63;
                    f16x4 vv;
#pragma unroll
                    for (int r = 0; r < 4; ++r)
                        vv[r] = (f16)fmaxf(acc[g][g2][blk * 4 + r] + bb, 0.0f);
                    *(f16x4*)&((f16*)out)[((size_t)(b_ * NH + h_) * HD + hd_) * S + s_] = vv;
                } else {
#pragma unroll
                    for (int r = 0; r < 4; ++r)
                        store_out(out, mode, row0 + r, col,
                                  fmaxf(acc[g][g2][blk * 4 + r] + bb, 0.0f));
                }
            }
    }
#else
    // Scalar fallback (correct; slow). Wf (and f16 A) stored swizzled.
    for (int i = tid; i < 128 * 128; i += 256) {
        const int m = bm * 128 + (i >> 7);
        const int n = bn * 128 + (i & 127);
        float acc = 0.0f;
        for (int k2 = 0; k2 < Dm; ++k2) {
            const float a = ADMA ? (float)((const f16*)A)[(size_t)m * Dm + swz(m, k2)]
                                 : ((const float*)A)[(size_t)m * Dm + k2];
            acc = fmaf(a, (float)Wf[(size_t)n * Dm + swz(n, k2)], acc);
        }
        store_out(out, mode, m, n, fmaxf(acc + bias[n], 0.0f));
    }
#endif
}

__global__ __launch_bounds__(256)
void gemm_qkv(const float* __restrict__ q, const float* __restrict__ k,
              const float* __restrict__ v, const f16* __restrict__ wqkv,
              const float* __restrict__ bq, const float* __restrict__ bk,
              const float* __restrict__ bv,
              f16* __restrict__ qh, f16* __restrict__ kh, f16* __restrict__ vt)
{
    const int z = blockIdx.z;
    const float* A = (z == 0) ? q : (z == 1) ? k : v;
    const float* B = (z == 0) ? bq : (z == 1) ? bk : bv;
    f16* O = (z == 0) ? qh : (z == 1) ? kh : vt;
    gemm_core<0>(A, wqkv + (size_t)z * Dm * Dm, B, O, (z == 2) ? 1 : 0);
}

__global__ __launch_bounds__(256)
void gemm_out(const f16* __restrict__ y, const f16* __restrict__ wo,
              const float* __restrict__ bo, float* __restrict__ out)
{
    gemm_core<1>(y, wo, bo, out, 2);
}

// ---------------------------------------------------------------------------
// Flash attention — unchanged round-10 kernel (passed); y stored with the NEW
// swz so gemm_out can DMA-stage it.
// ---------------------------------------------------------------------------
__global__ __launch_bounds__(256)
void attn_fwd(const f16* __restrict__ qh, const f16* __restrict__ kh,
              const f16* __restrict__ vt, f16* __restrict__ y)
{
    const int bz = blockIdx.x;       // B*H*(S/64) = 1024
    const int qt = bz & 15;
    const int h  = (bz >> 4) & 15;
    const int b  = bz >> 8;
    const size_t head = (size_t)(b * NH + h) * S * HD;

#if USE_A16
    __shared__ alignas(16) f16 Ks[2][64][72];
    __shared__ alignas(16) f16 Vs[2][64][72];

    const int tid  = threadIdx.x;
    const int wave = tid >> 6;
    const int lane = tid & 63;
    const int l15  = lane & 15;
    const int quad = lane >> 4;
    const int sr   = tid >> 2;
    const int sc   = (tid & 3) * 16;

    const f16* Qrow = qh + head + (size_t)(qt * 64 + wave * 16 + l15) * HD;
    const f16* Kp   = kh + head;
    const f16* Vp   = vt + head;

    f16x8 aq[2];
    {
        const uint4 q0 = *(const uint4*)(Qrow + quad * 16);
        const uint4 q1 = *(const uint4*)(Qrow + quad * 16 + 8);
        aq[0] = *(f16x8*)&q0;
        aq[1] = *(f16x8*)&q1;
    }

    const int qg = qt * 64 + wave * 16 + l15;
    float m_i = -1e30f, l_i = 0.0f;
    f32x4 acc_o[4] = {};

    uint4 pk[2], pv[2];
    auto pref = [&](int kt) {
        const f16* Kr = Kp + (size_t)(kt * 64 + sr) * HD + sc;
        pk[0] = *(const uint4*)Kr;
        pk[1] = *(const uint4*)(Kr + 8);
        const f16* Vr = Vp + (size_t)sr * S + kt * 64 + sc;
        pv[0] = *(const uint4*)Vr;
        pv[1] = *(const uint4*)(Vr + 8);
    };

    pref(0);
    for (int kt = 0; kt <= qt; ++kt) {
        const int cur = kt & 1;
        *(uint4*)&Ks[cur][sr][sc]     = pk[0];
        *(uint4*)&Ks[cur][sr][sc + 8] = pk[1];
        {
            const int sb = (sc >> 4) * 4;
            *(f16x4*)&Vs[cur][sr][0 * 16 + sb] = *(f16x4*)((f16*)&pv[0]);
            *(f16x4*)&Vs[cur][sr][1 * 16 + sb] = *(f16x4*)((f16*)&pv[0] + 4);
            *(f16x4*)&Vs[cur][sr][2 * 16 + sb] = *(f16x4*)((f16*)&pv[1]);
            *(f16x4*)&Vs[cur][sr][3 * 16 + sb] = *(f16x4*)((f16*)&pv[1] + 4);
        }
        __syncthreads();
        if (kt < qt) pref(kt + 1);

        f32x4 accs[4] = {};
#pragma unroll
        for (int t = 0; t < 4; ++t) {
            const f16x8 k8a = *(const f16x8*)&Ks[cur][t * 16 + l15][quad * 16];
            const f16x8 k8b = *(const f16x8*)&Ks[cur][t * 16 + l15][quad * 16 + 8];
            MFMA16K32(accs[t], k8a, aq[0]);
            MFMA16K32(accs[t], k8b, aq[1]);
        }

        const int key0 = kt * 64 + quad * 4;
#pragma unroll
        for (int t = 0; t < 4; ++t)
#pragma unroll
            for (int r = 0; r < 4; ++r) {
                float sv = accs[t][r] * 0.125f;
                if (key0 + t * 16 + r > qg) sv = -1e9f;
                accs[t][r] = sv;
            }

        float mx = accs[0][0];
#pragma unroll
        for (int t = 0; t < 4; ++t)
#pragma unroll
            for (int r = 0; r < 4; ++r) mx = fmaxf(mx, accs[t][r]);
        mx = fmaxf(mx, __shfl_xor(mx, 16, 64));
        mx = fmaxf(mx, __shfl_xor(mx, 32, 64));
        const float mnew = fmaxf(m_i, mx);
        float sm = 0.0f;
#pragma unroll
        for (int t = 0; t < 4; ++t)
#pragma unroll
            for (int r = 0; r < 4; ++r) {
                const float e = __expf(accs[t][r] - mnew);
                accs[t][r] = e;
                sm += e;
            }
        sm += __shfl_xor(sm, 16, 64);
        sm += __shfl_xor(sm, 32, 64);
        const float alpha = __expf(m_i - mnew);
        l_i = l_i * alpha + sm;
        m_i = mnew;

        f16x4 ap[4];
#pragma unroll
        for (int c = 0; c < 4; ++c) {
            f16x4 v;
#pragma unroll
            for (int j = 0; j < 4; ++j) v[j] = (f16)accs[c][j];
            ap[c] = v;
        }

        float ar[4];
#pragma unroll
        for (int r = 0; r < 4; ++r) ar[r] = __shfl(alpha, quad * 4 + r, 64);
#pragma unroll
        for (int t2 = 0; t2 < 4; ++t2)
#pragma unroll
            for (int r = 0; r < 4; ++r) acc_o[t2][r] *= ar[r];
#pragma unroll
        for (int t2 = 0; t2 < 4; ++t2) {
            const f16x8 v8a = *(const f16x8*)&Vs[cur][t2 * 16 + l15][quad * 16];
            const f16x8 v8b = *(const f16x8*)&Vs[cur][t2 * 16 + l15][quad * 16 + 8];
            MFMA16(acc_o[t2], ap[0], LO4(v8a));
            MFMA16(acc_o[t2], ap[1], HI4(v8a));
            MFMA16(acc_o[t2], ap[2], LO4(v8b));
            MFMA16(acc_o[t2], ap[3], HI4(v8b));
        }
    }

    float lr[4];
#pragma unroll
    for (int r = 0; r < 4; ++r) lr[r] = __shfl(l_i, quad * 4 + r, 64);
#pragma unroll
    for (int t2 = 0; t2 < 4; ++t2)
#pragma unroll
        for (int r = 0; r < 4; ++r) {
            const int srow = qt * 64 + wave * 16 + quad * 4 + r;
            const int dcol = h * 64 + t2 * 16 + l15;
            y[((size_t)b * S + srow) * Dm + swz(srow, dcol)] =
                (f16)(acc_o[t2][r] / lr[r]);
        }
#else
    const int tid = threadIdx.x;
    if (tid < 64) {
        const int q = qt * 64 + tid;
        const f16* Qr = qh + head + (size_t)q * HD;
        float qv[64];
        for (int d = 0; d < 64; ++d) qv[d] = (float)Qr[pcol64(d)];
        float mx = -1e30f;
        for (int key = 0; key <= q; ++key) {
            const f16* Kr = kh + head + (size_t)key * HD;
            float s = 0.0f;
            for (int d = 0; d < 64; ++d) s = fmaf(qv[d], (float)Kr[pcol64(d)], s);
            mx = fmaxf(mx, s * 0.125f);
        }
        float o[64];
        for (int d = 0; d < 64; ++d) o[d] = 0.0f;
        float l = 0.0f;
        for (int key = 0; key <= q; ++key) {
            const f16* Kr = kh + head + (size_t)key * HD;
            float s = 0.0f;
            for (int d = 0; d < 64; ++d) s = fmaf(qv[d], (float)Kr[pcol64(d)], s);
            const float p = __expf(s * 0.125f - mx);
            l += p;
            for (int d = 0; d < 64; ++d)
                o[d] = fmaf(p, (float)vt[head + (size_t)d * S + key], o[d]);
        }
        for (int d = 0; d < 64; ++d)
            y[((size_t)b * S + q) * Dm + swz(q, h * 64 + d)] = (f16)(o[d] / l);
    }
#endif
}

// ---------------------------------------------------------------------------
// ws layout (32 MB total, unchanged):
//   [0,8M)   qh            -> after attn: Wo f16 (2MB)
//   [8,16M)  kh
//   [16,24M) vt
//   [24,32M) Wq/Wk/Wv f16 (6MB, dead after gemm_qkv) -> y (8MB, from attn)
// ---------------------------------------------------------------------------
extern "C" void kernel_launch(void* const* d_in, const int* in_sizes, int n_in,
                              void* d_out, int out_size, void* d_ws, size_t ws_size,
                              hipStream_t stream)
{
    f16* ws = (f16*)d_ws;
    const size_t SEG = (size_t)4 * 1024 * 1024;   // 4M f16 = 8 MB per region
    f16* qh   = ws;
    f16* kh   = ws + SEG;
    f16* vt   = ws + 2 * SEG;
    f16* wqkv = ws + 3 * SEG;   // 3M f16, dead after gemm_qkv
    f16* y    = ws + 3 * SEG;   // attn overwrites the wqkv region
    f16* wo   = ws;             // Wo f16 into the dead qh region (after attn)

    cvt_w<<<dim3(1024, 3), 256, 0, stream>>>(
        (const float*)d_in[4], (const float*)d_in[6], (const float*)d_in[8], wqkv);
    gemm_qkv<<<dim3(32, 8, 3), 256, 0, stream>>>(
        (const float*)d_in[0], (const float*)d_in[1], (const float*)d_in[2],
        wqkv,
        (const float*)d_in[5], (const float*)d_in[7], (const float*)d_in[9],
        qh, kh, vt);
    // d_in[3] = causal tril mask, hardcoded
    attn_fwd<<<dim3(4 * NH * (S / 64)), 256, 0, stream>>>(qh, kh, vt, y);
    cvt_w<<<dim3(1024, 1), 256, 0, stream>>>(
        (const float*)d_in[10], nullptr, nullptr, wo);
    gemm_out<<<dim3(32, 8), 256, 0, stream>>>(
        y, wo, (const float*)d_in[11], (float*)d_out);
}

// Round 3
// 259.201 us; speedup vs baseline: 1.0595x; 1.0595x over previous
//
#include <hip/hip_runtime.h>

// Round 12: counted-vmcnt 3-buffer pipeline (T3/T4), fixed swizzle.
// - Round-11 post-mortem: ~9100 cy/K-step vs ~300 cy compute -> pure stall from
//   the depth-1 drain-barrier structure; BK changes can't fix it.
// - New K-loop: 3 LDS buffers, BK=32 (48 KB -> 3 blocks/CU), raw s_barrier +
//   s_waitcnt vmcnt(6|4) counted per-wave (qkv: prefA 4 + dma 2 per iter;
//   out: dma 4). DMA for tile t+2 issued at iter t -> 2 compute phases in
//   flight; vmcnt never drains to 0 until the last iter.
// - Correct swizzle for 64B rows: 16B-slot ^= (row>>1)&3 (8 consecutive rows
//   -> 8 distinct bank granules incl. row-parity bit). Applied to cvt_w's W
//   layout, attn's y store, stageA's ds_writes, and all frag reads.
// - gemm_qkv: A fp32 reg-staged (paA/paB named double-buffer, rule-20 safe),
//   issued BEFORE the dma each iter so compiler pa-waits keep DMAs in flight.
//   gemm_out: both operands DMA'd (y pre-swizzled by attn).
// Attention kernel unchanged (round-10/11 version, passing).

using f16    = _Float16;
using f16x4  = __attribute__((ext_vector_type(4))) _Float16;
using f16x8  = __attribute__((ext_vector_type(8))) _Float16;
using f32x4  = __attribute__((ext_vector_type(4))) float;
using f32x16 = __attribute__((ext_vector_type(16))) float;

static constexpr int S = 1024, Dm = 1024, NH = 16, HD = 64;

#if __has_builtin(__builtin_amdgcn_mfma_f32_32x32x16_f16)
#define USE_G32 1
#define MFMA32(ACC, A_, B_) \
    (ACC) = __builtin_amdgcn_mfma_f32_32x32x16_f16((A_), (B_), (ACC), 0, 0, 0)
#else
#define USE_G32 0
#endif

#if __has_builtin(__builtin_amdgcn_mfma_f32_16x16x32_f16) && \
    __has_builtin(__builtin_amdgcn_mfma_f32_16x16x16f16)
#define USE_A16 1
#define MFMA16K32(ACC, A_, B_) \
    (ACC) = __builtin_amdgcn_mfma_f32_16x16x32_f16((A_), (B_), (ACC), 0, 0, 0)
#define MFMA16(ACC, A_, B_) \
    (ACC) = __builtin_amdgcn_mfma_f32_16x16x16f16((A_), (B_), (ACC), 0, 0, 0)
#else
#define USE_A16 0
#endif

#define LO4(v) __builtin_shufflevector((v), (v), 0, 1, 2, 3)
#define HI4(v) __builtin_shufflevector((v), (v), 4, 5, 6, 7)

__device__ __forceinline__ f16x4 cvt4(float4 a) {
    f16x4 r; r[0] = (f16)a.x; r[1] = (f16)a.y; r[2] = (f16)a.z; r[3] = (f16)a.w;
    return r;
}

// hd permutation for qh/kh (K=32 QK MFMA), unchanged (verified round 10).
__device__ __forceinline__ int pcol64(int k) {
#if USE_A16
    return ((k >> 3) & 3) * 16 + ((k >> 5) << 3) + (k & 7);
#else
    return ((k >> 2) & 3) * 16 + ((k >> 4) << 2) + (k & 3);
#endif
}

// Bank swizzle for 32-f16 (64 B) row chunks: 16B-slot (2 bits) ^= (row>>1)&3.
// Bank granule = (row&1)*4 + slot -> 8 consecutive rows at fixed logical slot
// hit 8 distinct granules = conflict-free b128. Involution; writer==reader.
__device__ __forceinline__ int swz(int row, int col) {
    return (col & ~31) | ((((col >> 3) ^ (row >> 1)) & 3) << 3) | (col & 7);
}

// mode 0: [B,H,S,HD] f16 hd-permuted; 1: [B,H,HD,S] f16; 2: fp32 row-major
__device__ __forceinline__ void store_out(void* out, int mode, int m, int n, float v) {
    if (mode == 2) {
        ((float*)out)[(size_t)m * Dm + n] = v;
    } else {
        const int b_ = m >> 10, s_ = m & 1023, h_ = n >> 6, hd_ = n & 63;
        const size_t idx = (mode == 0)
            ? (((size_t)(b_ * NH + h_) * S + s_) * HD + pcol64(hd_))
            : (((size_t)(b_ * NH + h_) * HD + hd_) * S + s_);
        ((f16*)out)[idx] = (f16)v;
    }
}

#if __has_builtin(__builtin_amdgcn_global_load_lds)
#define HAS_GLL 1
#else
#define HAS_GLL 0
#endif

__device__ __forceinline__ void gll16(const f16* g, f16* l) {
#if HAS_GLL
    __builtin_amdgcn_global_load_lds(
        (const __attribute__((address_space(1))) void*)g,
        (__attribute__((address_space(3))) void*)l, 16, 0, 0);
#else
    *(uint4*)l = *(const uint4*)g;   // sync fallback; barrier structure still valid
#endif
}

// ---------------------------------------------------------------------------
// fp32 W -> f16, swizzled layout. grid (1024, nmat); one float4 per thread.
// k&7 in {0,4}: a float4 stays inside one 8-f16 slot, so swz maps it cleanly.
// ---------------------------------------------------------------------------
__global__ __launch_bounds__(256)
void cvt_w(const float* __restrict__ s0, const float* __restrict__ s1,
           const float* __restrict__ s2, f16* __restrict__ dst)
{
    const int z = blockIdx.y;
    const float* src = (z == 0) ? s0 : (z == 1) ? s1 : s2;
    const int e = blockIdx.x * 256 + threadIdx.x;   // float4 id within matrix
    const int n = e >> 8;
    const int k = (e & 255) * 4;
    const float4 v = *(const float4*)(src + (size_t)n * Dm + k);
    *(f16x4*)(dst + (size_t)z * Dm * Dm + (size_t)n * Dm + swz(n, k)) = cvt4(v);
}

// ---------------------------------------------------------------------------
// out = relu(A @ W^T + bias). 128x128 tile, BK=32, 3-buffer counted-vmcnt
// pipeline, 4 waves (2x2), 64x64/wave via 2x2 32x32 frags, 8 MFMA/iter/wave.
// Per-iter per-wave vmem issue (fixed order!):  [prefA:4 (qkv only)] [dma:2|4]
// Steady-state wait at iter t: dma(t) done, {prefA(t+1),dma(t+1)} in flight
//   -> vmcnt(6) (qkv) / vmcnt(4) (out); vmcnt(0) only on the last iter.
// dma(t+2) issued AFTER the barrier of iter t (buf (t+2)%3 == buf (t-1)%3 was
// read at iter t-1; barrier confirms all waves done).
// ---------------------------------------------------------------------------
template <int ADMA>
__device__ __forceinline__ void gemm_core(const void* __restrict__ A,
                                          const f16* __restrict__ Wf,
                                          const float* __restrict__ bias,
                                          void* __restrict__ out, int mode)
{
    const int tid = threadIdx.x;
    const int bm = blockIdx.x, bn = blockIdx.y;
#if USE_G32
    __shared__ alignas(16) f16 As[3][128][32];   // 24 KB
    __shared__ alignas(16) f16 Ws[3][128][32];   // 24 KB (total 48 -> 3 blk/CU)

    const int lane = tid & 63, wave = tid >> 6;
    const int l31 = lane & 31, kh = lane >> 5;
    const int wm = wave & 1, wn = wave >> 1;

    // DMA: chunk = 16 rows x 32 f16 = 1KB; LDS dest = wave*1024 + lane*16
    // (wave-uniform base + lane*16, the HW rule). Wave w stages rows
    // [w*16,+16) and [64+w*16,+16) of the 128-row tile.
    const int drow = wave * 16 + (lane >> 2);
    const int dcol = (lane & 3) * 8;
    const f16* Wsrc = Wf + (size_t)(bn * 128 + drow) * Dm + dcol;
    const f16* Asrc = (const f16*)A + (size_t)(bm * 128 + drow) * Dm + dcol;

    auto dma = [&](int k0, int buf) {
        gll16(Wsrc + k0, &Ws[buf][drow][dcol]);
        gll16(Wsrc + k0 + (size_t)64 * Dm, &Ws[buf][64 + drow][dcol]);
        if (ADMA) {
            gll16(Asrc + k0, &As[buf][drow][dcol]);
            gll16(Asrc + k0 + (size_t)64 * Dm, &As[buf][64 + drow][dcol]);
        }
    };

    // fp32 A reg staging (ADMA=0): 2 threads/row, 16 fp32 each (4 float4).
    const int ar = tid >> 1, ah = tid & 1;
    const float* Af = (const float*)A + (size_t)(bm * 128 + ar) * Dm + ah * 16;

    auto prefA = [&](int k0, float4 (&pa)[4]) {
#pragma unroll
        for (int j = 0; j < 4; ++j) pa[j] = *(const float4*)(Af + k0 + j * 4);
    };
    auto stageA = [&](int buf, const float4 (&pa)[4]) {
#pragma unroll
        for (int j2 = 0; j2 < 2; ++j2) {
            f16x8 v;
            const float4 a0 = pa[j2 * 2], a1 = pa[j2 * 2 + 1];
            v[0] = (f16)a0.x; v[1] = (f16)a0.y; v[2] = (f16)a0.z; v[3] = (f16)a0.w;
            v[4] = (f16)a1.x; v[5] = (f16)a1.y; v[6] = (f16)a1.z; v[7] = (f16)a1.w;
            const int phys = ((ah * 2 + j2) ^ ((ar >> 1) & 3)) & 3;
            *(f16x8*)&As[buf][ar][phys * 8] = v;     // conflict-free (verified map)
        }
    };

    f32x16 acc[2][2] = {};

    auto kslice = [&](int buf, int s) {
        const int sl = s * 2 + kh;
        const int rA0 = wm * 64 + l31,  rA1 = wm * 64 + 32 + l31;
        const int rB0 = wn * 64 + l31,  rB1 = wn * 64 + 32 + l31;
        const f16x8 af0 = *(const f16x8*)&As[buf][rA0][((sl ^ ((rA0 >> 1) & 3)) & 3) * 8];
        const f16x8 af1 = *(const f16x8*)&As[buf][rA1][((sl ^ ((rA1 >> 1) & 3)) & 3) * 8];
        const f16x8 bf0 = *(const f16x8*)&Ws[buf][rB0][((sl ^ ((rB0 >> 1) & 3)) & 3) * 8];
        const f16x8 bf1 = *(const f16x8*)&Ws[buf][rB1][((sl ^ ((rB1 >> 1) & 3)) & 3) * 8];
        MFMA32(acc[0][0], af0, bf0);
        MFMA32(acc[0][1], af0, bf1);
        MFMA32(acc[1][0], af1, bf0);
        MFMA32(acc[1][1], af1, bf1);
    };

    constexpr int NIT = Dm / 32;   // 32
    float4 paA[4], paB[4];

    // Prologue: issue order pins the vmcnt bookkeeping.
    if (!ADMA) prefA(0, paA);
    dma(0, 0);
    if (!ADMA) prefA(32, paB);
    dma(32, 1);
    if (!ADMA) stageA(0, paA);     // compiler waits paA (vmcnt(8)), DMAs stay in flight

    auto iter = [&](int t, float4 (&pnew)[4], const float4 (&pold)[4]) {
        if (t < NIT - 1) {
            if (ADMA) asm volatile("s_waitcnt vmcnt(4)" ::: "memory");
            else      asm volatile("s_waitcnt vmcnt(6)" ::: "memory");
        } else {
            asm volatile("s_waitcnt vmcnt(0)" ::: "memory");
        }
        asm volatile("s_waitcnt lgkmcnt(0)" ::: "memory");   // my ds_writes visible
        __builtin_amdgcn_s_barrier();
        __builtin_amdgcn_sched_barrier(0);                    // no reads hoist above
        const int cb = t % 3;
        if (t + 2 < NIT) {
            if (!ADMA) prefA((t + 2) * 32, pnew);             // BEFORE dma: ordering!
            dma((t + 2) * 32, (t + 2) % 3);
        }
        kslice(cb, 0);
        if (!ADMA && t + 1 < NIT) stageA((t + 1) % 3, pold);
        kslice(cb, 1);
    };

    for (int t = 0; t < NIT; t += 2) {
        iter(t, paA, paB);        // pa(t+2) -> slot (t+2)&1 = 0 = paA; consumes paB
        iter(t + 1, paB, paA);
    }

    // epilogue (C/D map verified in round 10)
#pragma unroll
    for (int g2 = 0; g2 < 2; ++g2) {
        const int col = bn * 128 + wn * 64 + g2 * 32 + l31;
        const float bb = bias[col];
#pragma unroll
        for (int g = 0; g < 2; ++g)
#pragma unroll
            for (int blk = 0; blk < 4; ++blk) {
                const int row0 = bm * 128 + wm * 64 + g * 32 + 8 * blk + 4 * kh;
                if (mode == 1) {   // [B,H,HD,S]: 4 consecutive s -> packed b64
                    const int b_ = row0 >> 10, s_ = row0 & 1023;
                    const int h_ = col >> 6, hd_ = col & 63;
                    f16x4 vv;
#pragma unroll
                    for (int r = 0; r < 4; ++r)
                        vv[r] = (f16)fmaxf(acc[g][g2][blk * 4 + r] + bb, 0.0f);
                    *(f16x4*)&((f16*)out)[((size_t)(b_ * NH + h_) * HD + hd_) * S + s_] = vv;
                } else {
#pragma unroll
                    for (int r = 0; r < 4; ++r)
                        store_out(out, mode, row0 + r, col,
                                  fmaxf(acc[g][g2][blk * 4 + r] + bb, 0.0f));
                }
            }
    }
#else
    // Scalar fallback (correct; slow). Wf (and f16 A) stored swizzled.
    for (int i = tid; i < 128 * 128; i += 256) {
        const int m = bm * 128 + (i >> 7);
        const int n = bn * 128 + (i & 127);
        float acc = 0.0f;
        for (int k2 = 0; k2 < Dm; ++k2) {
            const float a = ADMA ? (float)((const f16*)A)[(size_t)m * Dm + swz(m, k2)]
                                 : ((const float*)A)[(size_t)m * Dm + k2];
            acc = fmaf(a, (float)Wf[(size_t)n * Dm + swz(n, k2)], acc);
        }
        store_out(out, mode, m, n, fmaxf(acc + bias[n], 0.0f));
    }
#endif
}

__global__ __launch_bounds__(256, 3)
void gemm_qkv(const float* __restrict__ q, const float* __restrict__ k,
              const float* __restrict__ v, const f16* __restrict__ wqkv,
              const float* __restrict__ bq, const float* __restrict__ bk,
              const float* __restrict__ bv,
              f16* __restrict__ qh, f16* __restrict__ kh, f16* __restrict__ vt)
{
    const int z = blockIdx.z;
    const float* A = (z == 0) ? q : (z == 1) ? k : v;
    const float* B = (z == 0) ? bq : (z == 1) ? bk : bv;
    f16* O = (z == 0) ? qh : (z == 1) ? kh : vt;
    gemm_core<0>(A, wqkv + (size_t)z * Dm * Dm, B, O, (z == 2) ? 1 : 0);
}

__global__ __launch_bounds__(256, 3)
void gemm_out(const f16* __restrict__ y, const f16* __restrict__ wo,
              const float* __restrict__ bo, float* __restrict__ out)
{
    gemm_core<1>(y, wo, bo, out, 2);
}

// ---------------------------------------------------------------------------
// Flash attention — unchanged (passing); y stored with the NEW swz so
// gemm_out can DMA-stage it.
// ---------------------------------------------------------------------------
__global__ __launch_bounds__(256)
void attn_fwd(const f16* __restrict__ qh, const f16* __restrict__ kh,
              const f16* __restrict__ vt, f16* __restrict__ y)
{
    const int bz = blockIdx.x;       // B*H*(S/64) = 1024
    const int qt = bz & 15;
    const int h  = (bz >> 4) & 15;
    const int b  = bz >> 8;
    const size_t head = (size_t)(b * NH + h) * S * HD;

#if USE_A16
    __shared__ alignas(16) f16 Ks[2][64][72];
    __shared__ alignas(16) f16 Vs[2][64][72];

    const int tid  = threadIdx.x;
    const int wave = tid >> 6;
    const int lane = tid & 63;
    const int l15  = lane & 15;
    const int quad = lane >> 4;
    const int sr   = tid >> 2;
    const int sc   = (tid & 3) * 16;

    const f16* Qrow = qh + head + (size_t)(qt * 64 + wave * 16 + l15) * HD;
    const f16* Kp   = kh + head;
    const f16* Vp   = vt + head;

    f16x8 aq[2];
    {
        const uint4 q0 = *(const uint4*)(Qrow + quad * 16);
        const uint4 q1 = *(const uint4*)(Qrow + quad * 16 + 8);
        aq[0] = *(f16x8*)&q0;
        aq[1] = *(f16x8*)&q1;
    }

    const int qg = qt * 64 + wave * 16 + l15;
    float m_i = -1e30f, l_i = 0.0f;
    f32x4 acc_o[4] = {};

    uint4 pk[2], pv[2];
    auto pref = [&](int kt) {
        const f16* Kr = Kp + (size_t)(kt * 64 + sr) * HD + sc;
        pk[0] = *(const uint4*)Kr;
        pk[1] = *(const uint4*)(Kr + 8);
        const f16* Vr = Vp + (size_t)sr * S + kt * 64 + sc;
        pv[0] = *(const uint4*)Vr;
        pv[1] = *(const uint4*)(Vr + 8);
    };

    pref(0);
    for (int kt = 0; kt <= qt; ++kt) {
        const int cur = kt & 1;
        *(uint4*)&Ks[cur][sr][sc]     = pk[0];
        *(uint4*)&Ks[cur][sr][sc + 8] = pk[1];
        {
            const int sb = (sc >> 4) * 4;
            *(f16x4*)&Vs[cur][sr][0 * 16 + sb] = *(f16x4*)((f16*)&pv[0]);
            *(f16x4*)&Vs[cur][sr][1 * 16 + sb] = *(f16x4*)((f16*)&pv[0] + 4);
            *(f16x4*)&Vs[cur][sr][2 * 16 + sb] = *(f16x4*)((f16*)&pv[1]);
            *(f16x4*)&Vs[cur][sr][3 * 16 + sb] = *(f16x4*)((f16*)&pv[1] + 4);
        }
        __syncthreads();
        if (kt < qt) pref(kt + 1);

        f32x4 accs[4] = {};
#pragma unroll
        for (int t = 0; t < 4; ++t) {
            const f16x8 k8a = *(const f16x8*)&Ks[cur][t * 16 + l15][quad * 16];
            const f16x8 k8b = *(const f16x8*)&Ks[cur][t * 16 + l15][quad * 16 + 8];
            MFMA16K32(accs[t], k8a, aq[0]);
            MFMA16K32(accs[t], k8b, aq[1]);
        }

        const int key0 = kt * 64 + quad * 4;
#pragma unroll
        for (int t = 0; t < 4; ++t)
#pragma unroll
            for (int r = 0; r < 4; ++r) {
                float sv = accs[t][r] * 0.125f;
                if (key0 + t * 16 + r > qg) sv = -1e9f;
                accs[t][r] = sv;
            }

        float mx = accs[0][0];
#pragma unroll
        for (int t = 0; t < 4; ++t)
#pragma unroll
            for (int r = 0; r < 4; ++r) mx = fmaxf(mx, accs[t][r]);
        mx = fmaxf(mx, __shfl_xor(mx, 16, 64));
        mx = fmaxf(mx, __shfl_xor(mx, 32, 64));
        const float mnew = fmaxf(m_i, mx);
        float sm = 0.0f;
#pragma unroll
        for (int t = 0; t < 4; ++t)
#pragma unroll
            for (int r = 0; r < 4; ++r) {
                const float e = __expf(accs[t][r] - mnew);
                accs[t][r] = e;
                sm += e;
            }
        sm += __shfl_xor(sm, 16, 64);
        sm += __shfl_xor(sm, 32, 64);
        const float alpha = __expf(m_i - mnew);
        l_i = l_i * alpha + sm;
        m_i = mnew;

        f16x4 ap[4];
#pragma unroll
        for (int c = 0; c < 4; ++c) {
            f16x4 v;
#pragma unroll
            for (int j = 0; j < 4; ++j) v[j] = (f16)accs[c][j];
            ap[c] = v;
        }

        float ar[4];
#pragma unroll
        for (int r = 0; r < 4; ++r) ar[r] = __shfl(alpha, quad * 4 + r, 64);
#pragma unroll
        for (int t2 = 0; t2 < 4; ++t2)
#pragma unroll
            for (int r = 0; r < 4; ++r) acc_o[t2][r] *= ar[r];
#pragma unroll
        for (int t2 = 0; t2 < 4; ++t2) {
            const f16x8 v8a = *(const f16x8*)&Vs[cur][t2 * 16 + l15][quad * 16];
            const f16x8 v8b = *(const f16x8*)&Vs[cur][t2 * 16 + l15][quad * 16 + 8];
            MFMA16(acc_o[t2], ap[0], LO4(v8a));
            MFMA16(acc_o[t2], ap[1], HI4(v8a));
            MFMA16(acc_o[t2], ap[2], LO4(v8b));
            MFMA16(acc_o[t2], ap[3], HI4(v8b));
        }
    }

    float lr[4];
#pragma unroll
    for (int r = 0; r < 4; ++r) lr[r] = __shfl(l_i, quad * 4 + r, 64);
#pragma unroll
    for (int t2 = 0; t2 < 4; ++t2)
#pragma unroll
        for (int r = 0; r < 4; ++r) {
            const int srow = qt * 64 + wave * 16 + quad * 4 + r;
            const int dcol = h * 64 + t2 * 16 + l15;
            y[((size_t)b * S + srow) * Dm + swz(srow, dcol)] =
                (f16)(acc_o[t2][r] / lr[r]);
        }
#else
    const int tid = threadIdx.x;
    if (tid < 64) {
        const int q = qt * 64 + tid;
        const f16* Qr = qh + head + (size_t)q * HD;
        float qv[64];
        for (int d = 0; d < 64; ++d) qv[d] = (float)Qr[pcol64(d)];
        float mx = -1e30f;
        for (int key = 0; key <= q; ++key) {
            const f16* Kr = kh + head + (size_t)key * HD;
            float s = 0.0f;
            for (int d = 0; d < 64; ++d) s = fmaf(qv[d], (float)Kr[pcol64(d)], s);
            mx = fmaxf(mx, s * 0.125f);
        }
        float o[64];
        for (int d = 0; d < 64; ++d) o[d] = 0.0f;
        float l = 0.0f;
        for (int key = 0; key <= q; ++key) {
            const f16* Kr = kh + head + (size_t)key * HD;
            float s = 0.0f;
            for (int d = 0; d < 64; ++d) s = fmaf(qv[d], (float)Kr[pcol64(d)], s);
            const float p = __expf(s * 0.125f - mx);
            l += p;
            for (int d = 0; d < 64; ++d)
                o[d] = fmaf(p, (float)vt[head + (size_t)d * S + key], o[d]);
        }
        for (int d = 0; d < 64; ++d)
            y[((size_t)b * S + q) * Dm + swz(q, h * 64 + d)] = (f16)(o[d] / l);
    }
#endif
}

// ---------------------------------------------------------------------------
// ws layout (32 MB total, unchanged):
//   [0,8M)   qh            -> after attn: Wo f16 (2MB)
//   [8,16M)  kh
//   [16,24M) vt
//   [24,32M) Wq/Wk/Wv f16 (6MB, dead after gemm_qkv) -> y (8MB, from attn)
// ---------------------------------------------------------------------------
extern "C" void kernel_launch(void* const* d_in, const int* in_sizes, int n_in,
                              void* d_out, int out_size, void* d_ws, size_t ws_size,
                              hipStream_t stream)
{
    f16* ws = (f16*)d_ws;
    const size_t SEG = (size_t)4 * 1024 * 1024;   // 4M f16 = 8 MB per region
    f16* qh   = ws;
    f16* kh   = ws + SEG;
    f16* vt   = ws + 2 * SEG;
    f16* wqkv = ws + 3 * SEG;   // 3M f16, dead after gemm_qkv
    f16* y    = ws + 3 * SEG;   // attn overwrites the wqkv region
    f16* wo   = ws;             // Wo f16 into the dead qh region (after attn)

    cvt_w<<<dim3(1024, 3), 256, 0, stream>>>(
        (const float*)d_in[4], (const float*)d_in[6], (const float*)d_in[8], wqkv);
    gemm_qkv<<<dim3(32, 8, 3), 256, 0, stream>>>(
        (const float*)d_in[0], (const float*)d_in[1], (const float*)d_in[2],
        wqkv,
        (const float*)d_in[5], (const float*)d_in[7], (const float*)d_in[9],
        qh, kh, vt);
    // d_in[3] = causal tril mask, hardcoded
    attn_fwd<<<dim3(4 * NH * (S / 64)), 256, 0, stream>>>(qh, kh, vt, y);
    cvt_w<<<dim3(1024, 1), 256, 0, stream>>>(
        (const float*)d_in[10], nullptr, nullptr, wo);
    gemm_out<<<dim3(32, 8), 256, 0, stream>>>(
        y, wo, (const float*)d_in[11], (float*)d_out);
}

// Round 4
// 252.612 us; speedup vs baseline: 1.0872x; 1.0261x over previous
//
#include <hip/hip_runtime.h>

// Round 13: 8-wave (512-thread) 128x128 GEMM blocks — occupancy attack.
// Evidence: rounds 10-12 perf tracked resident waves (77/91/77 us at occ
// 28/16/23%), all pipes <15% busy, iter time 5775 cy vs 768 cy MFMA floor ->
// latency-bound. Grid is fixed at 768 blocks (3/CU); doubling waves/block
// 4->8 doubles resident waves to 24/CU (and gemm_out 4->8, it has been at
// 1 block/CU all along). Per-wave tile 32x64 (2 MFMA/k-slice, 4/iter).
// Counted-vmcnt 3-buffer pipeline kept (round-12 semantics, counts redone):
//   qkv per-iter issue: prefA x2 (fp32 A), dma x1 (W) -> steady vmcnt(3)
//   out per-iter issue: dma x2 (A+W)                  -> steady vmcnt(2)
// Staging per thread halves; W DMA = exactly 1 gll16/thread (512*16B = 8KB
// buffer, dest byte = tid*16, linear rule OK). Swizzles/layouts unchanged.
// Attention + cvt_w kernels unchanged (passing since round 10).

using f16    = _Float16;
using f16x4  = __attribute__((ext_vector_type(4))) _Float16;
using f16x8  = __attribute__((ext_vector_type(8))) _Float16;
using f32x4  = __attribute__((ext_vector_type(4))) float;
using f32x16 = __attribute__((ext_vector_type(16))) float;

static constexpr int S = 1024, Dm = 1024, NH = 16, HD = 64;

#if __has_builtin(__builtin_amdgcn_mfma_f32_32x32x16_f16)
#define USE_G32 1
#define MFMA32(ACC, A_, B_) \
    (ACC) = __builtin_amdgcn_mfma_f32_32x32x16_f16((A_), (B_), (ACC), 0, 0, 0)
#else
#define USE_G32 0
#endif

#if __has_builtin(__builtin_amdgcn_mfma_f32_16x16x32_f16) && \
    __has_builtin(__builtin_amdgcn_mfma_f32_16x16x16f16)
#define USE_A16 1
#define MFMA16K32(ACC, A_, B_) \
    (ACC) = __builtin_amdgcn_mfma_f32_16x16x32_f16((A_), (B_), (ACC), 0, 0, 0)
#define MFMA16(ACC, A_, B_) \
    (ACC) = __builtin_amdgcn_mfma_f32_16x16x16f16((A_), (B_), (ACC), 0, 0, 0)
#else
#define USE_A16 0
#endif

#define LO4(v) __builtin_shufflevector((v), (v), 0, 1, 2, 3)
#define HI4(v) __builtin_shufflevector((v), (v), 4, 5, 6, 7)

__device__ __forceinline__ f16x4 cvt4(float4 a) {
    f16x4 r; r[0] = (f16)a.x; r[1] = (f16)a.y; r[2] = (f16)a.z; r[3] = (f16)a.w;
    return r;
}

// hd permutation for qh/kh (K=32 QK MFMA), unchanged (verified round 10).
__device__ __forceinline__ int pcol64(int k) {
#if USE_A16
    return ((k >> 3) & 3) * 16 + ((k >> 5) << 3) + (k & 7);
#else
    return ((k >> 2) & 3) * 16 + ((k >> 4) << 2) + (k & 3);
#endif
}

// Bank swizzle for 32-f16 (64 B) row chunks: 16B-slot (2 bits) ^= (row>>1)&3.
// Granule = (row&1)*4 + slot^((row>>1)&3): 8 consecutive rows at a fixed
// logical slot hit 8 distinct granules -> conflict-free b128. Involution.
__device__ __forceinline__ int swz(int row, int col) {
    return (col & ~31) | ((((col >> 3) ^ (row >> 1)) & 3) << 3) | (col & 7);
}

// mode 0: [B,H,S,HD] f16 hd-permuted; 1: [B,H,HD,S] f16; 2: fp32 row-major
__device__ __forceinline__ void store_out(void* out, int mode, int m, int n, float v) {
    if (mode == 2) {
        ((float*)out)[(size_t)m * Dm + n] = v;
    } else {
        const int b_ = m >> 10, s_ = m & 1023, h_ = n >> 6, hd_ = n & 63;
        const size_t idx = (mode == 0)
            ? (((size_t)(b_ * NH + h_) * S + s_) * HD + pcol64(hd_))
            : (((size_t)(b_ * NH + h_) * HD + hd_) * S + s_);
        ((f16*)out)[idx] = (f16)v;
    }
}

#if __has_builtin(__builtin_amdgcn_global_load_lds)
#define HAS_GLL 1
#else
#define HAS_GLL 0
#endif

__device__ __forceinline__ void gll16(const f16* g, f16* l) {
#if HAS_GLL
    __builtin_amdgcn_global_load_lds(
        (const __attribute__((address_space(1))) void*)g,
        (__attribute__((address_space(3))) void*)l, 16, 0, 0);
#else
    *(uint4*)l = *(const uint4*)g;   // sync fallback; barrier structure still valid
#endif
}

// ---------------------------------------------------------------------------
// fp32 W -> f16, swizzled layout. grid (1024, nmat); one float4 per thread.
// ---------------------------------------------------------------------------
__global__ __launch_bounds__(256)
void cvt_w(const float* __restrict__ s0, const float* __restrict__ s1,
           const float* __restrict__ s2, f16* __restrict__ dst)
{
    const int z = blockIdx.y;
    const float* src = (z == 0) ? s0 : (z == 1) ? s1 : s2;
    const int e = blockIdx.x * 256 + threadIdx.x;   // float4 id within matrix
    const int n = e >> 8;
    const int k = (e & 255) * 4;
    const float4 v = *(const float4*)(src + (size_t)n * Dm + k);
    *(f16x4*)(dst + (size_t)z * Dm * Dm + (size_t)n * Dm + swz(n, k)) = cvt4(v);
}

// ---------------------------------------------------------------------------
// out = relu(A @ W^T + bias). 128x128 tile, BK=32, 3-buffer counted-vmcnt
// pipeline, 8 waves; per-wave out 32x64 (wm=wave&3 row-group, wn=wave>>2
// col-group), 2x 32x32x16 MFMA per k-slice, 4/iter.
// Issue order per iter (fixed): [prefA:2 (qkv)] [dma:1|2]; steady wait
// vmcnt(3) (qkv) / vmcnt(2) (out) drains exactly dma(t); vmcnt(0) last iter.
// ---------------------------------------------------------------------------
template <int ADMA>
__device__ __forceinline__ void gemm_core(const void* __restrict__ A,
                                          const f16* __restrict__ Wf,
                                          const float* __restrict__ bias,
                                          void* __restrict__ out, int mode)
{
    const int tid = threadIdx.x;
    const int bm = blockIdx.x, bn = blockIdx.y;
#if USE_G32
    __shared__ alignas(16) f16 As[3][128][32];   // 24 KB
    __shared__ alignas(16) f16 Ws[3][128][32];   // 24 KB (48 total -> 3 blk/CU)

    const int lane = tid & 63, wave = tid >> 6;
    const int l31 = lane & 31, kh = lane >> 5;
    const int wm = wave & 3, wn = wave >> 2;     // 4 row-groups x 2 col-groups

    // DMA: 512 threads cover the full 128x32 buffer; dest byte = tid*16
    // (wave-base + lane*16, HW-linear). One gll16 per thread per operand.
    const int drow = tid >> 2;
    const int dcol = (tid & 3) * 8;
    const f16* Wsrc = Wf + (size_t)(bn * 128 + drow) * Dm + dcol;
    const f16* Asrc = (const f16*)A + (size_t)(bm * 128 + drow) * Dm + dcol;

    auto dma = [&](int k0, int buf) {
        gll16(Wsrc + k0, &Ws[buf][drow][dcol]);
        if (ADMA) gll16(Asrc + k0, &As[buf][drow][dcol]);
    };

    // fp32 A reg staging (ADMA=0): 4 threads/row, 8 fp32 each (2 float4).
    const int ar = tid >> 2, aslot = tid & 3;
    const float* Af = (const float*)A + (size_t)(bm * 128 + ar) * Dm + aslot * 8;

    auto prefA = [&](int k0, float4 (&pa)[2]) {
        pa[0] = *(const float4*)(Af + k0);
        pa[1] = *(const float4*)(Af + k0 + 4);
    };
    auto stageA = [&](int buf, const float4 (&pa)[2]) {
        f16x8 v;
        v[0] = (f16)pa[0].x; v[1] = (f16)pa[0].y; v[2] = (f16)pa[0].z; v[3] = (f16)pa[0].w;
        v[4] = (f16)pa[1].x; v[5] = (f16)pa[1].y; v[6] = (f16)pa[1].z; v[7] = (f16)pa[1].w;
        const int phys = (aslot ^ ((ar >> 1) & 3)) & 3;
        *(f16x8*)&As[buf][ar][phys * 8] = v;     // 2-way max per 16-lane phase
    };

    f32x16 acc[2] = {};

    auto kslice = [&](int buf, int s) {
        const int sl = s * 2 + kh;               // logical 16B slot (0..3)
        const int rA = wm * 32 + l31;
        const int rB0 = wn * 64 + l31, rB1 = wn * 64 + 32 + l31;
        const f16x8 af  = *(const f16x8*)&As[buf][rA][((sl ^ ((rA >> 1) & 3)) & 3) * 8];
        const f16x8 bf0 = *(const f16x8*)&Ws[buf][rB0][((sl ^ ((rB0 >> 1) & 3)) & 3) * 8];
        const f16x8 bf1 = *(const f16x8*)&Ws[buf][rB1][((sl ^ ((rB1 >> 1) & 3)) & 3) * 8];
        MFMA32(acc[0], af, bf0);
        MFMA32(acc[1], af, bf1);
    };

    constexpr int NIT = Dm / 32;   // 32
    float4 paA[2], paB[2];

    // Prologue (issue order pins vmcnt bookkeeping).
    if (!ADMA) prefA(0, paA);
    dma(0, 0);
    if (!ADMA) prefA(32, paB);
    dma(32, 1);
    if (!ADMA) stageA(0, paA);     // waits paA; dmas stay in flight (older? no:
                                   // prefA(0) oldest -> drains nothing newer)

    auto iter = [&](int t, float4 (&pnew)[2], const float4 (&pold)[2]) {
        if (t < NIT - 1) {
            if (ADMA) asm volatile("s_waitcnt vmcnt(2)" ::: "memory");
            else      asm volatile("s_waitcnt vmcnt(3)" ::: "memory");
        } else {
            asm volatile("s_waitcnt vmcnt(0)" ::: "memory");
        }
        asm volatile("s_waitcnt lgkmcnt(0)" ::: "memory");   // my ds_writes visible
        __builtin_amdgcn_s_barrier();
        __builtin_amdgcn_sched_barrier(0);                    // no hoisting above
        const int cb = t % 3;
        if (t + 2 < NIT) {
            if (!ADMA) prefA((t + 2) * 32, pnew);             // BEFORE dma: ordering
            dma((t + 2) * 32, (t + 2) % 3);
        }
        kslice(cb, 0);
        if (!ADMA && t + 1 < NIT) stageA((t + 1) % 3, pold);
        kslice(cb, 1);
    };

    for (int t = 0; t < NIT; t += 2) {
        iter(t, paA, paB);
        iter(t + 1, paB, paA);
    }

    // epilogue: C/D map (verified): reg i -> row = 8*(i>>2)+4*kh+(i&3), col=l31
#pragma unroll
    for (int j = 0; j < 2; ++j) {
        const int col = bn * 128 + wn * 64 + j * 32 + l31;
        const float bb = bias[col];
#pragma unroll
        for (int blk = 0; blk < 4; ++blk) {
            const int row0 = bm * 128 + wm * 32 + 8 * blk + 4 * kh;
            if (mode == 1) {   // [B,H,HD,S]: 4 consecutive s -> packed b64
                const int b_ = row0 >> 10, s_ = row0 & 1023;
                const int h_ = col >> 6, hd_ = col & 63;
                f16x4 vv;
#pragma unroll
                for (int r = 0; r < 4; ++r)
                    vv[r] = (f16)fmaxf(acc[j][blk * 4 + r] + bb, 0.0f);
                *(f16x4*)&((f16*)out)[((size_t)(b_ * NH + h_) * HD + hd_) * S + s_] = vv;
            } else {
#pragma unroll
                for (int r = 0; r < 4; ++r)
                    store_out(out, mode, row0 + r, col,
                              fmaxf(acc[j][blk * 4 + r] + bb, 0.0f));
            }
        }
    }
#else
    // Scalar fallback (correct; slow). Wf (and f16 A) stored swizzled.
    for (int i = tid; i < 128 * 128; i += 512) {
        const int m = bm * 128 + (i >> 7);
        const int n = bn * 128 + (i & 127);
        float acc = 0.0f;
        for (int k2 = 0; k2 < Dm; ++k2) {
            const float a = ADMA ? (float)((const f16*)A)[(size_t)m * Dm + swz(m, k2)]
                                 : ((const float*)A)[(size_t)m * Dm + k2];
            acc = fmaf(a, (float)Wf[(size_t)n * Dm + swz(n, k2)], acc);
        }
        store_out(out, mode, m, n, fmaxf(acc + bias[n], 0.0f));
    }
#endif
}

__global__ __launch_bounds__(512, 6)
void gemm_qkv(const float* __restrict__ q, const float* __restrict__ k,
              const float* __restrict__ v, const f16* __restrict__ wqkv,
              const float* __restrict__ bq, const float* __restrict__ bk,
              const float* __restrict__ bv,
              f16* __restrict__ qh, f16* __restrict__ kh, f16* __restrict__ vt)
{
    const int z = blockIdx.z;
    const float* A = (z == 0) ? q : (z == 1) ? k : v;
    const float* B = (z == 0) ? bq : (z == 1) ? bk : bv;
    f16* O = (z == 0) ? qh : (z == 1) ? kh : vt;
    gemm_core<0>(A, wqkv + (size_t)z * Dm * Dm, B, O, (z == 2) ? 1 : 0);
}

__global__ __launch_bounds__(512, 2)
void gemm_out(const f16* __restrict__ y, const f16* __restrict__ wo,
              const float* __restrict__ bo, float* __restrict__ out)
{
    gemm_core<1>(y, wo, bo, out, 2);
}

// ---------------------------------------------------------------------------
// Flash attention — unchanged (passing); y stored swizzled for gemm_out DMA.
// ---------------------------------------------------------------------------
__global__ __launch_bounds__(256)
void attn_fwd(const f16* __restrict__ qh, const f16* __restrict__ kh,
              const f16* __restrict__ vt, f16* __restrict__ y)
{
    const int bz = blockIdx.x;       // B*H*(S/64) = 1024
    const int qt = bz & 15;
    const int h  = (bz >> 4) & 15;
    const int b  = bz >> 8;
    const size_t head = (size_t)(b * NH + h) * S * HD;

#if USE_A16
    __shared__ alignas(16) f16 Ks[2][64][72];
    __shared__ alignas(16) f16 Vs[2][64][72];

    const int tid  = threadIdx.x;
    const int wave = tid >> 6;
    const int lane = tid & 63;
    const int l15  = lane & 15;
    const int quad = lane >> 4;
    const int sr   = tid >> 2;
    const int sc   = (tid & 3) * 16;

    const f16* Qrow = qh + head + (size_t)(qt * 64 + wave * 16 + l15) * HD;
    const f16* Kp   = kh + head;
    const f16* Vp   = vt + head;

    f16x8 aq[2];
    {
        const uint4 q0 = *(const uint4*)(Qrow + quad * 16);
        const uint4 q1 = *(const uint4*)(Qrow + quad * 16 + 8);
        aq[0] = *(f16x8*)&q0;
        aq[1] = *(f16x8*)&q1;
    }

    const int qg = qt * 64 + wave * 16 + l15;
    float m_i = -1e30f, l_i = 0.0f;
    f32x4 acc_o[4] = {};

    uint4 pk[2], pv[2];
    auto pref = [&](int kt) {
        const f16* Kr = Kp + (size_t)(kt * 64 + sr) * HD + sc;
        pk[0] = *(const uint4*)Kr;
        pk[1] = *(const uint4*)(Kr + 8);
        const f16* Vr = Vp + (size_t)sr * S + kt * 64 + sc;
        pv[0] = *(const uint4*)Vr;
        pv[1] = *(const uint4*)(Vr + 8);
    };

    pref(0);
    for (int kt = 0; kt <= qt; ++kt) {
        const int cur = kt & 1;
        *(uint4*)&Ks[cur][sr][sc]     = pk[0];
        *(uint4*)&Ks[cur][sr][sc + 8] = pk[1];
        {
            const int sb = (sc >> 4) * 4;
            *(f16x4*)&Vs[cur][sr][0 * 16 + sb] = *(f16x4*)((f16*)&pv[0]);
            *(f16x4*)&Vs[cur][sr][1 * 16 + sb] = *(f16x4*)((f16*)&pv[0] + 4);
            *(f16x4*)&Vs[cur][sr][2 * 16 + sb] = *(f16x4*)((f16*)&pv[1]);
            *(f16x4*)&Vs[cur][sr][3 * 16 + sb] = *(f16x4*)((f16*)&pv[1] + 4);
        }
        __syncthreads();
        if (kt < qt) pref(kt + 1);

        f32x4 accs[4] = {};
#pragma unroll
        for (int t = 0; t < 4; ++t) {
            const f16x8 k8a = *(const f16x8*)&Ks[cur][t * 16 + l15][quad * 16];
            const f16x8 k8b = *(const f16x8*)&Ks[cur][t * 16 + l15][quad * 16 + 8];
            MFMA16K32(accs[t], k8a, aq[0]);
            MFMA16K32(accs[t], k8b, aq[1]);
        }

        const int key0 = kt * 64 + quad * 4;
#pragma unroll
        for (int t = 0; t < 4; ++t)
#pragma unroll
            for (int r = 0; r < 4; ++r) {
                float sv = accs[t][r] * 0.125f;
                if (key0 + t * 16 + r > qg) sv = -1e9f;
                accs[t][r] = sv;
            }

        float mx = accs[0][0];
#pragma unroll
        for (int t = 0; t < 4; ++t)
#pragma unroll
            for (int r = 0; r < 4; ++r) mx = fmaxf(mx, accs[t][r]);
        mx = fmaxf(mx, __shfl_xor(mx, 16, 64));
        mx = fmaxf(mx, __shfl_xor(mx, 32, 64));
        const float mnew = fmaxf(m_i, mx);
        float sm = 0.0f;
#pragma unroll
        for (int t = 0; t < 4; ++t)
#pragma unroll
            for (int r = 0; r < 4; ++r) {
                const float e = __expf(accs[t][r] - mnew);
                accs[t][r] = e;
                sm += e;
            }
        sm += __shfl_xor(sm, 16, 64);
        sm += __shfl_xor(sm, 32, 64);
        const float alpha = __expf(m_i - mnew);
        l_i = l_i * alpha + sm;
        m_i = mnew;

        f16x4 ap[4];
#pragma unroll
        for (int c = 0; c < 4; ++c) {
            f16x4 v;
#pragma unroll
            for (int j = 0; j < 4; ++j) v[j] = (f16)accs[c][j];
            ap[c] = v;
        }

        float ar[4];
#pragma unroll
        for (int r = 0; r < 4; ++r) ar[r] = __shfl(alpha, quad * 4 + r, 64);
#pragma unroll
        for (int t2 = 0; t2 < 4; ++t2)
#pragma unroll
            for (int r = 0; r < 4; ++r) acc_o[t2][r] *= ar[r];
#pragma unroll
        for (int t2 = 0; t2 < 4; ++t2) {
            const f16x8 v8a = *(const f16x8*)&Vs[cur][t2 * 16 + l15][quad * 16];
            const f16x8 v8b = *(const f16x8*)&Vs[cur][t2 * 16 + l15][quad * 16 + 8];
            MFMA16(acc_o[t2], ap[0], LO4(v8a));
            MFMA16(acc_o[t2], ap[1], HI4(v8a));
            MFMA16(acc_o[t2], ap[2], LO4(v8b));
            MFMA16(acc_o[t2], ap[3], HI4(v8b));
        }
    }

    float lr[4];
#pragma unroll
    for (int r = 0; r < 4; ++r) lr[r] = __shfl(l_i, quad * 4 + r, 64);
#pragma unroll
    for (int t2 = 0; t2 < 4; ++t2)
#pragma unroll
        for (int r = 0; r < 4; ++r) {
            const int srow = qt * 64 + wave * 16 + quad * 4 + r;
            const int dcol = h * 64 + t2 * 16 + l15;
            y[((size_t)b * S + srow) * Dm + swz(srow, dcol)] =
                (f16)(acc_o[t2][r] / lr[r]);
        }
#else
    const int tid = threadIdx.x;
    if (tid < 64) {
        const int q = qt * 64 + tid;
        const f16* Qr = qh + head + (size_t)q * HD;
        float qv[64];
        for (int d = 0; d < 64; ++d) qv[d] = (float)Qr[pcol64(d)];
        float mx = -1e30f;
        for (int key = 0; key <= q; ++key) {
            const f16* Kr = kh + head + (size_t)key * HD;
            float s = 0.0f;
            for (int d = 0; d < 64; ++d) s = fmaf(qv[d], (float)Kr[pcol64(d)], s);
            mx = fmaxf(mx, s * 0.125f);
        }
        float o[64];
        for (int d = 0; d < 64; ++d) o[d] = 0.0f;
        float l = 0.0f;
        for (int key = 0; key <= q; ++key) {
            const f16* Kr = kh + head + (size_t)key * HD;
            float s = 0.0f;
            for (int d = 0; d < 64; ++d) s = fmaf(qv[d], (float)Kr[pcol64(d)], s);
            const float p = __expf(s * 0.125f - mx);
            l += p;
            for (int d = 0; d < 64; ++d)
                o[d] = fmaf(p, (float)vt[head + (size_t)d * S + key], o[d]);
        }
        for (int d = 0; d < 64; ++d)
            y[((size_t)b * S + q) * Dm + swz(q, h * 64 + d)] = (f16)(o[d] / l);
    }
#endif
}

// ---------------------------------------------------------------------------
// ws layout (32 MB total, unchanged):
//   [0,8M)   qh            -> after attn: Wo f16 (2MB)
//   [8,16M)  kh
//   [16,24M) vt
//   [24,32M) Wq/Wk/Wv f16 (6MB, dead after gemm_qkv) -> y (8MB, from attn)
// ---------------------------------------------------------------------------
extern "C" void kernel_launch(void* const* d_in, const int* in_sizes, int n_in,
                              void* d_out, int out_size, void* d_ws, size_t ws_size,
                              hipStream_t stream)
{
    f16* ws = (f16*)d_ws;
    const size_t SEG = (size_t)4 * 1024 * 1024;   // 4M f16 = 8 MB per region
    f16* qh   = ws;
    f16* kh   = ws + SEG;
    f16* vt   = ws + 2 * SEG;
    f16* wqkv = ws + 3 * SEG;   // 3M f16, dead after gemm_qkv
    f16* y    = ws + 3 * SEG;   // attn overwrites the wqkv region
    f16* wo   = ws;             // Wo f16 into the dead qh region (after attn)

    cvt_w<<<dim3(1024, 3), 256, 0, stream>>>(
        (const float*)d_in[4], (const float*)d_in[6], (const float*)d_in[8], wqkv);
    gemm_qkv<<<dim3(32, 8, 3), 512, 0, stream>>>(
        (const float*)d_in[0], (const float*)d_in[1], (const float*)d_in[2],
        wqkv,
        (const float*)d_in[5], (const float*)d_in[7], (const float*)d_in[9],
        qh, kh, vt);
    // d_in[3] = causal tril mask, hardcoded
    attn_fwd<<<dim3(4 * NH * (S / 64)), 256, 0, stream>>>(qh, kh, vt, y);
    cvt_w<<<dim3(1024, 1), 256, 0, stream>>>(
        (const float*)d_in[10], nullptr, nullptr, wo);
    gemm_out<<<dim3(32, 8), 512, 0, stream>>>(
        y, wo, (const float*)d_in[11], (float*)d_out);
}